// Round 2
// baseline (1169.764 us; speedup 1.0000x reference)
//
#include <hip/hip_runtime.h>
#include <hip/hip_bf16.h>

// Problem constants
#define D_M   512
#define H_M   1024
#define G_N   8
#define E_N   8
#define T_N   1024
#define NEXP  64
#define CAP   1024

#define LDK   520          // padded K row stride for xl (bf16 elems): 520*2=1040 B, 16B-aligned

typedef __attribute__((ext_vector_type(8))) short bf16x8;
typedef __attribute__((ext_vector_type(4))) float f32x4;
typedef __attribute__((ext_vector_type(4))) unsigned int u32x4;

// single-instruction packed f32->bf16 (RNE)
__device__ __forceinline__ unsigned pack2(float a, float b) {
  unsigned r;
  asm("v_cvt_pk_bf16_f32 %0, %1, %2" : "=v"(r) : "v"(a), "v"(b));
  return r;
}
__device__ __forceinline__ unsigned short f2bf(float f) {
  unsigned u = __builtin_bit_cast(unsigned, f);
  u = (u + 0x7fffu + ((u >> 16) & 1u)) >> 16;   // RTN-even
  return (unsigned short)u;
}

// ---------------- routing (fp32, exact) + expert-list build (merged) ----------------
__global__ __launch_bounds__(64) void k_route(
    const float* __restrict__ x, const float* __restrict__ g1,
    const float* __restrict__ g2, float* __restrict__ slotW,
    int* __restrict__ counts, int* __restrict__ list) {
  __shared__ float xs[D_M];
  __shared__ float l2s[G_N][E_N];
  __shared__ float l1s[G_N];
  __shared__ float l1part[G_N][8];
  const int t = blockIdx.x;
  const int lane = threadIdx.x;
  const float* xr = x + (size_t)t * D_M;
  for (int i = lane; i < D_M; i += 64) xs[i] = xr[i];
  __syncthreads();
  {
    const int g = lane >> 3, e = lane & 7;
    const float* gp = g2 + (size_t)g * D_M * E_N + e;
    float acc = 0.f;
    #pragma unroll 8
    for (int i = 0; i < D_M; i++) acc += xs[i] * gp[(size_t)i * E_N];
    l2s[g][e] = acc;
  }
  {
    const int g = lane >> 3, c = lane & 7;
    float acc = 0.f;
    #pragma unroll 8
    for (int i = c * 64; i < c * 64 + 64; i++) acc += xs[i] * g1[(size_t)i * G_N + g];
    l1part[g][c] = acc;
  }
  __syncthreads();
  if (lane < G_N) {
    float s = 0.f;
    #pragma unroll
    for (int c = 0; c < 8; c++) s += l1part[lane][c];
    l1s[lane] = s;
  }
  __syncthreads();
  if (lane == 0) {
    int a1 = 0;
    for (int g = 1; g < G_N; g++) if (l1s[g] > l1s[a1]) a1 = g;
    int a2 = (a1 == 0) ? 1 : 0;
    for (int g = 0; g < G_N; g++) if (g != a1 && l1s[g] > l1s[a2]) a2 = g;
    const float m = l1s[a1];
    float w1a = __expf(l1s[a1] - m), w1b = __expf(l1s[a2] - m);
    const float inv = 1.f / (w1a + w1b);
    w1a *= inv; w1b *= inv;
    const int gsel[2] = {a1, a2};
    const float wsel[2] = {w1a, w1b};
    for (int a = 0; a < 2; a++) {
      const int g = gsel[a];
      int e1 = 0;
      for (int e = 1; e < E_N; e++) if (l2s[g][e] > l2s[g][e1]) e1 = e;
      int e2 = (e1 == 0) ? 1 : 0;
      for (int e = 0; e < E_N; e++) if (e != e1 && l2s[g][e] > l2s[g][e2]) e2 = e;
      const float mm = l2s[g][e1];
      float ua = __expf(l2s[g][e1] - mm), ub = __expf(l2s[g][e2] - mm);
      const float uin = 1.f / (ua + ub);
      ua *= uin; ub *= uin;
      const int ge0 = g * E_N + e1;
      const int ge1 = g * E_N + e2;
      slotW[t * 4 + a * 2 + 0] = wsel[a] * ua;
      slotW[t * 4 + a * 2 + 1] = wsel[a] * ub;
      int p0 = atomicAdd(&counts[ge0], 1);
      list[ge0 * CAP + p0] = t * 4 + a * 2 + 0;
      int p1 = atomicAdd(&counts[ge1], 1);
      list[ge1 * CAP + p1] = t * 4 + a * 2 + 1;
    }
  }
}

// ---------------- GEMM1: h = relu(x @ W1 + b1) -> bf16. Barrier-free K-loop ----------------
// grid: 64 ge x 8 j-tiles(128) x 4 token-tiles. block 256 = 4 waves; wave owns 32 j (nt=2), 64 tokens (mt=4).
// W prefetched 2 K-steps ahead through a 3-slot rotating register buffer (full unroll -> static idx).
__global__ __launch_bounds__(256, 2) void k_mlp1(
    const float* __restrict__ x, const float* __restrict__ W1,
    const float* __restrict__ b1, const int* __restrict__ counts,
    const int* __restrict__ list, unsigned short* __restrict__ h_ws) {
  const int bx = blockIdx.x;
  const int ge = bx >> 5;
  const int j0 = ((bx >> 2) & 7) * 128;
  const int tt = bx & 3;
  const int n = counts[ge];
  if (tt * 64 >= n) return;
  __shared__ unsigned short xl[64 * LDK];   // [token][k] full-K, bf16
  __shared__ int tokTS[64];
  const int tid = threadIdx.x;
  const int lane = tid & 63, wave = tid >> 6;
  const int m16 = lane & 15, quad = lane >> 4;

  const float* Wcol = W1 + (size_t)ge * (D_M * H_M) + j0 + wave * 32 + m16;
  float bv[2];
  #pragma unroll
  for (int nt = 0; nt < 2; nt++) bv[nt] = b1[ge * H_M + j0 + wave * 32 + nt * 16 + m16];

  for (int t0 = tt * 64; t0 < n; t0 += 256) {
    __syncthreads();
    if (tid < 64) {
      int idx = t0 + tid;
      tokTS[tid] = list[ge * CAP + (idx < n ? idx : n - 1)];
    }
    __syncthreads();
    // stage x (fp32 -> bf16): thread covers token tid>>2, k-lane (tid&3)*4, 32 reps of 16 floats
    {
      const int trow = tid >> 2;
      const int kb = (tid & 3) * 4;
      const float* xr = x + (size_t)(tokTS[trow] >> 2) * D_M + kb;
      unsigned short* dst = &xl[trow * LDK + kb];
      #pragma unroll 8
      for (int rep = 0; rep < 32; rep++) {
        f32x4 v = *(const f32x4*)(xr + rep * 16);
        uint2 p = { pack2(v.x, v.y), pack2(v.z, v.w) };
        *(uint2*)(dst + rep * 16) = p;
      }
    }
    __syncthreads();

    f32x4 acc[4][2] = {};
    float bw[3][2][8];
    // prologue: prefetch s=0 and s=1
    #pragma unroll
    for (int p = 0; p < 2; p++)
      #pragma unroll
      for (int nt = 0; nt < 2; nt++)
        #pragma unroll
        for (int i = 0; i < 8; i++)
          bw[p][nt][i] = Wcol[(size_t)(p * 32 + quad * 8 + i) * H_M + nt * 16];

    #pragma unroll
    for (int s = 0; s < 16; s++) {       // K = 512, no barriers, full unroll
      if (s + 2 < 16) {
        #pragma unroll
        for (int nt = 0; nt < 2; nt++)
          #pragma unroll
          for (int i = 0; i < 8; i++)
            bw[(s + 2) % 3][nt][i] = Wcol[(size_t)((s + 2) * 32 + quad * 8 + i) * H_M + nt * 16];
      }
      bf16x8 bf[2];
      #pragma unroll
      for (int nt = 0; nt < 2; nt++) {
        const int c = s % 3;
        u32x4 t = { pack2(bw[c][nt][0], bw[c][nt][1]), pack2(bw[c][nt][2], bw[c][nt][3]),
                    pack2(bw[c][nt][4], bw[c][nt][5]), pack2(bw[c][nt][6], bw[c][nt][7]) };
        bf[nt] = __builtin_bit_cast(bf16x8, t);
      }
      #pragma unroll
      for (int mt = 0; mt < 4; mt++) {
        bf16x8 af = *(bf16x8*)&xl[(mt * 16 + m16) * LDK + s * 32 + quad * 8];
        acc[mt][0] = __builtin_amdgcn_mfma_f32_16x16x32_bf16(af, bf[0], acc[mt][0], 0, 0, 0);
        acc[mt][1] = __builtin_amdgcn_mfma_f32_16x16x32_bf16(af, bf[1], acc[mt][1], 0, 0, 0);
      }
    }
    // epilogue: bias + relu -> bf16
    #pragma unroll
    for (int mt = 0; mt < 4; mt++)
      #pragma unroll
      for (int i = 0; i < 4; i++) {
        const int tr = mt * 16 + quad * 4 + i;
        if (t0 + tr < n) {
          const int ts = tokTS[tr];
          unsigned short* hp = h_ws + (size_t)ts * H_M + j0 + wave * 32 + m16;
          #pragma unroll
          for (int nt = 0; nt < 2; nt++) {
            float v = acc[mt][nt][i] + bv[nt];
            hp[nt * 16] = f2bf(v > 0.f ? v : 0.f);
          }
        }
      }
  }
}

// ---------------- GEMM2: y_part = h @ W2 (+b2 on ks=0) -> fp32, K-split 2, barrier-free ----------------
// grid: 64 ge x 4 j-tiles(128) x 2 ksplit x 4 token-tiles. Same depth-2 W prefetch.
__global__ __launch_bounds__(256, 2) void k_mlp2(
    const unsigned short* __restrict__ h_ws, const float* __restrict__ W2,
    const float* __restrict__ b2, const int* __restrict__ counts,
    const int* __restrict__ list, float* __restrict__ y0,
    float* __restrict__ y1) {
  const int bx = blockIdx.x;
  const int ge = bx >> 5;
  const int j0 = ((bx >> 3) & 3) * 128;
  const int ks = (bx >> 2) & 1;
  const int tt = bx & 3;
  const int n = counts[ge];
  if (tt * 64 >= n) return;
  __shared__ unsigned short xl[64 * LDK];   // [token][k-half], bf16
  __shared__ int tokTS[64];
  const int tid = threadIdx.x;
  const int lane = tid & 63, wave = tid >> 6;
  const int m16 = lane & 15, quad = lane >> 4;

  const float* Wcol = W2 + (size_t)ge * (H_M * D_M) + (size_t)(ks * 512) * D_M + j0 + wave * 32 + m16;
  float bv[2];
  #pragma unroll
  for (int nt = 0; nt < 2; nt++)
    bv[nt] = ks == 0 ? b2[ge * D_M + j0 + wave * 32 + nt * 16 + m16] : 0.f;
  float* yk = ks == 0 ? y0 : y1;

  for (int t0 = tt * 64; t0 < n; t0 += 256) {
    __syncthreads();
    if (tid < 64) {
      int idx = t0 + tid;
      tokTS[tid] = list[ge * CAP + (idx < n ? idx : n - 1)];
    }
    __syncthreads();
    // stage h-half (already bf16): thread covers token tid>>2, k-lane (tid&3)*8, 16 reps of 32 elems
    {
      const int trow = tid >> 2;
      const int kb = (tid & 3) * 8;
      const unsigned short* hr = h_ws + (size_t)tokTS[trow] * H_M + ks * 512 + kb;
      unsigned short* dst = &xl[trow * LDK + kb];
      #pragma unroll 8
      for (int rep = 0; rep < 16; rep++)
        *(u32x4*)(dst + rep * 32) = *(const u32x4*)(hr + rep * 32);
    }
    __syncthreads();

    f32x4 acc[4][2] = {};
    float bw[3][2][8];
    #pragma unroll
    for (int p = 0; p < 2; p++)
      #pragma unroll
      for (int nt = 0; nt < 2; nt++)
        #pragma unroll
        for (int i = 0; i < 8; i++)
          bw[p][nt][i] = Wcol[(size_t)(p * 32 + quad * 8 + i) * D_M + nt * 16];

    #pragma unroll
    for (int s = 0; s < 16; s++) {       // K-half = 512, full unroll
      if (s + 2 < 16) {
        #pragma unroll
        for (int nt = 0; nt < 2; nt++)
          #pragma unroll
          for (int i = 0; i < 8; i++)
            bw[(s + 2) % 3][nt][i] = Wcol[(size_t)((s + 2) * 32 + quad * 8 + i) * D_M + nt * 16];
      }
      bf16x8 bf[2];
      #pragma unroll
      for (int nt = 0; nt < 2; nt++) {
        const int c = s % 3;
        u32x4 t = { pack2(bw[c][nt][0], bw[c][nt][1]), pack2(bw[c][nt][2], bw[c][nt][3]),
                    pack2(bw[c][nt][4], bw[c][nt][5]), pack2(bw[c][nt][6], bw[c][nt][7]) };
        bf[nt] = __builtin_bit_cast(bf16x8, t);
      }
      #pragma unroll
      for (int mt = 0; mt < 4; mt++) {
        bf16x8 af = *(bf16x8*)&xl[(mt * 16 + m16) * LDK + s * 32 + quad * 8];
        acc[mt][0] = __builtin_amdgcn_mfma_f32_16x16x32_bf16(af, bf[0], acc[mt][0], 0, 0, 0);
        acc[mt][1] = __builtin_amdgcn_mfma_f32_16x16x32_bf16(af, bf[1], acc[mt][1], 0, 0, 0);
      }
    }
    #pragma unroll
    for (int mt = 0; mt < 4; mt++)
      #pragma unroll
      for (int i = 0; i < 4; i++) {
        const int tr = mt * 16 + quad * 4 + i;
        if (t0 + tr < n) {
          const int ts = tokTS[tr];
          float* yp = yk + (size_t)ts * D_M + j0 + wave * 32 + m16;
          #pragma unroll
          for (int nt = 0; nt < 2; nt++)
            yp[nt * 16] = acc[mt][nt][i] + bv[nt];
        }
      }
  }
}

// ---------------- combine: out[t] = sum_s slotW[t,s] * (y0+y1)[t*4+s] ----------------
__global__ __launch_bounds__(256) void k_combine(
    const float* __restrict__ y0, const float* __restrict__ y1,
    const float* __restrict__ slotW, float* __restrict__ out) {
  const int idx = blockIdx.x * 256 + threadIdx.x;
  if (idx >= T_N * D_M / 4) return;
  const int t = idx >> 7;
  const int j = (idx & 127) * 4;
  float4 r = {0.f, 0.f, 0.f, 0.f};
  #pragma unroll
  for (int s = 0; s < 4; s++) {
    const float w = slotW[t * 4 + s];
    const size_t off = (size_t)(t * 4 + s) * D_M + j;
    const float4 a = *(const float4*)(y0 + off);
    const float4 b = *(const float4*)(y1 + off);
    r.x += w * (a.x + b.x);
    r.y += w * (a.y + b.y);
    r.z += w * (a.z + b.z);
    r.w += w * (a.w + b.w);
  }
  *(float4*)&out[(size_t)t * D_M + j] = r;
}

// ---------------- launch ----------------
extern "C" void kernel_launch(void* const* d_in, const int* in_sizes, int n_in,
                              void* d_out, int out_size, void* d_ws, size_t ws_size,
                              hipStream_t stream) {
  const float* x  = (const float*)d_in[0];
  const float* g1 = (const float*)d_in[1];
  const float* g2 = (const float*)d_in[2];
  const float* W1 = (const float*)d_in[3];
  const float* b1 = (const float*)d_in[4];
  const float* W2 = (const float*)d_in[5];
  const float* b2 = (const float*)d_in[6];
  float* out = (float*)d_out;

  char* ws = (char*)d_ws;
  float*          slotW  = (float*)(ws + 16384);               // 4096 floats
  int*            counts = (int*)(ws + 32768);                 // 64 ints
  int*            list   = (int*)(ws + 36864);                 // 64*1024 ints (256 KB)
  unsigned short* h_ws   = (unsigned short*)(ws + 524288);     // 4096*1024 bf16 (8 MB)
  float*          y0     = (float*)(ws + 524288 + 8388608);    // 4096*512 f32 (8 MB)
  float*          y1     = (float*)(ws + 524288 + 16777216);   // 4096*512 f32 (8 MB)

  hipMemsetAsync(counts, 0, NEXP * sizeof(int), stream);
  k_route<<<T_N, 64, 0, stream>>>(x, g1, g2, slotW, counts, list);
  k_mlp1<<<NEXP * 32, 256, 0, stream>>>(x, W1, b1, counts, list, h_ws);
  k_mlp2<<<NEXP * 32, 256, 0, stream>>>(h_ws, W2, b2, counts, list, y0, y1);
  k_combine<<<(T_N * D_M / 4) / 256, 256, 0, stream>>>(y0, y1, slotW, out);
}

// Round 3
// 432.804 us; speedup vs baseline: 2.7028x; 2.7028x over previous
//
#include <hip/hip_runtime.h>
#include <hip/hip_bf16.h>

// Problem constants
#define D_M   512
#define H_M   1024
#define G_N   8
#define E_N   8
#define T_N   1024
#define NEXP  64
#define CAP   1024

#define LDK   520          // padded K row stride for xl (bf16 elems): 520*2=1040 B, 16B-aligned

typedef __attribute__((ext_vector_type(8))) short bf16x8;
typedef __attribute__((ext_vector_type(4))) float f32x4;
typedef __attribute__((ext_vector_type(4))) unsigned int u32x4;

// single-instruction packed f32->bf16 (RNE)
__device__ __forceinline__ unsigned pack2(float a, float b) {
  unsigned r;
  asm("v_cvt_pk_bf16_f32 %0, %1, %2" : "=v"(r) : "v"(a), "v"(b));
  return r;
}
__device__ __forceinline__ unsigned short f2bf(float f) {
  unsigned u = __builtin_bit_cast(unsigned, f);
  u = (u + 0x7fffu + ((u >> 16) & 1u)) >> 16;   // RTN-even
  return (unsigned short)u;
}

// ---------------- routing (fp32, exact) + expert-list build (merged) ----------------
__global__ __launch_bounds__(64) void k_route(
    const float* __restrict__ x, const float* __restrict__ g1,
    const float* __restrict__ g2, float* __restrict__ slotW,
    int* __restrict__ counts, int* __restrict__ list) {
  __shared__ float xs[D_M];
  __shared__ float l2s[G_N][E_N];
  __shared__ float l1s[G_N];
  __shared__ float l1part[G_N][8];
  const int t = blockIdx.x;
  const int lane = threadIdx.x;
  const float* xr = x + (size_t)t * D_M;
  for (int i = lane; i < D_M; i += 64) xs[i] = xr[i];
  __syncthreads();
  {
    const int g = lane >> 3, e = lane & 7;
    const float* gp = g2 + (size_t)g * D_M * E_N + e;
    float acc = 0.f;
    #pragma unroll 8
    for (int i = 0; i < D_M; i++) acc += xs[i] * gp[(size_t)i * E_N];
    l2s[g][e] = acc;
  }
  {
    const int g = lane >> 3, c = lane & 7;
    float acc = 0.f;
    #pragma unroll 8
    for (int i = c * 64; i < c * 64 + 64; i++) acc += xs[i] * g1[(size_t)i * G_N + g];
    l1part[g][c] = acc;
  }
  __syncthreads();
  if (lane < G_N) {
    float s = 0.f;
    #pragma unroll
    for (int c = 0; c < 8; c++) s += l1part[lane][c];
    l1s[lane] = s;
  }
  __syncthreads();
  if (lane == 0) {
    int a1 = 0;
    for (int g = 1; g < G_N; g++) if (l1s[g] > l1s[a1]) a1 = g;
    int a2 = (a1 == 0) ? 1 : 0;
    for (int g = 0; g < G_N; g++) if (g != a1 && l1s[g] > l1s[a2]) a2 = g;
    const float m = l1s[a1];
    float w1a = __expf(l1s[a1] - m), w1b = __expf(l1s[a2] - m);
    const float inv = 1.f / (w1a + w1b);
    w1a *= inv; w1b *= inv;
    const int gsel[2] = {a1, a2};
    const float wsel[2] = {w1a, w1b};
    for (int a = 0; a < 2; a++) {
      const int g = gsel[a];
      int e1 = 0;
      for (int e = 1; e < E_N; e++) if (l2s[g][e] > l2s[g][e1]) e1 = e;
      int e2 = (e1 == 0) ? 1 : 0;
      for (int e = 0; e < E_N; e++) if (e != e1 && l2s[g][e] > l2s[g][e2]) e2 = e;
      const float mm = l2s[g][e1];
      float ua = __expf(l2s[g][e1] - mm), ub = __expf(l2s[g][e2] - mm);
      const float uin = 1.f / (ua + ub);
      ua *= uin; ub *= uin;
      const int ge0 = g * E_N + e1;
      const int ge1 = g * E_N + e2;
      slotW[t * 4 + a * 2 + 0] = wsel[a] * ua;
      slotW[t * 4 + a * 2 + 1] = wsel[a] * ub;
      int p0 = atomicAdd(&counts[ge0], 1);
      list[ge0 * CAP + p0] = t * 4 + a * 2 + 0;
      int p1 = atomicAdd(&counts[ge1], 1);
      list[ge1 * CAP + p1] = t * 4 + a * 2 + 1;
    }
  }
}

// ---------------- prepack: W1/W2 fp32 -> bf16 in MFMA-fragment order ----------------
// Wt1 frag index f = (ge*64 + jb)*16 + s   (jb = j/16 in 0..63, s = k/32 in 0..15)
// Wt2 frag index f = (ge*32 + jb)*32 + s   (jb = j/16 in 0..31, s = k/32 in 0..31)
// Each frag: 64 lanes x 8 bf16 (16 B): lane=(m16,quad) holds W[k=s*32+quad*8+i][j=jb*16+m16], i=0..7.
// Blocks 0..511: W1 (ge=b>>3, jt128=b&7). Blocks 512..1023: W2 (ge=(b-512)>>3, jt=((b-512)>>1)&3, sh=(b-512)&1).
__global__ __launch_bounds__(256) void k_pack(
    const float* __restrict__ W1, const float* __restrict__ W2,
    unsigned short* __restrict__ Wt1, unsigned short* __restrict__ Wt2) {
  const int b = blockIdx.x;
  const int tid = threadIdx.x;
  if (b < 512) {
    const int ge = b >> 3, jt = b & 7;
    const float* Wsrc = W1 + (size_t)ge * (D_M * H_M);
    #pragma unroll 2
    for (int iter = 0; iter < 32; iter++) {
      const int unit = iter * 256 + tid;           // 8192 units: jbl(8) x s(16) x lane(64)
      const int lane = unit & 63;
      const int s = (unit >> 6) & 15;
      const int jbl = unit >> 10;
      const int j = jt * 128 + jbl * 16 + (lane & 15);
      const int k = s * 32 + (lane >> 4) * 8;
      const float* src = Wsrc + (size_t)k * H_M + j;
      float v[8];
      #pragma unroll
      for (int i = 0; i < 8; i++) v[i] = src[(size_t)i * H_M];
      u32x4 o = { pack2(v[0], v[1]), pack2(v[2], v[3]), pack2(v[4], v[5]), pack2(v[6], v[7]) };
      *(u32x4*)(Wt1 + ((size_t)((ge * 64 + jt * 8 + jbl) * 16 + s) * 64 + lane) * 8) = o;
    }
  } else {
    const int b2 = b - 512;
    const int ge = b2 >> 3, jt = (b2 >> 1) & 3, sh = b2 & 1;
    const float* Wsrc = W2 + (size_t)ge * (H_M * D_M);
    #pragma unroll 2
    for (int iter = 0; iter < 32; iter++) {
      const int unit = iter * 256 + tid;           // jbl(8) x s16(16) x lane(64)
      const int lane = unit & 63;
      const int s16 = (unit >> 6) & 15;
      const int jbl = unit >> 10;
      const int s = sh * 16 + s16;
      const int jb2 = jt * 8 + jbl;
      const int j = jb2 * 16 + (lane & 15);
      const int k = s * 32 + (lane >> 4) * 8;
      const float* src = Wsrc + (size_t)k * D_M + j;
      float v[8];
      #pragma unroll
      for (int i = 0; i < 8; i++) v[i] = src[(size_t)i * D_M];
      u32x4 o = { pack2(v[0], v[1]), pack2(v[2], v[3]), pack2(v[4], v[5]), pack2(v[6], v[7]) };
      *(u32x4*)(Wt2 + ((size_t)((ge * 32 + jb2) * 32 + s) * 64 + lane) * 8) = o;
    }
  }
}

// ---------------- GEMM1: h = relu(x @ W1 + b1) -> bf16. Prepacked W, linear frag loads ----------------
// grid: 64 ge x 8 j-tiles(128). block 256 = 4 waves; wave owns 32 j (nt=2), all 64 tokens (mt=4).
__global__ __launch_bounds__(256, 2) void k_mlp1(
    const float* __restrict__ x, const unsigned short* __restrict__ Wt1,
    const float* __restrict__ b1, const int* __restrict__ counts,
    const int* __restrict__ list, unsigned short* __restrict__ h_ws) {
  const int ge = blockIdx.x >> 3;
  const int jt = blockIdx.x & 7;
  const int j0 = jt * 128;
  const int n = counts[ge];
  if (n == 0) return;
  __shared__ unsigned short xl[64 * LDK];   // [token][k] full-K, bf16
  __shared__ int tokTS[64];
  const int tid = threadIdx.x;
  const int lane = tid & 63, wave = tid >> 6;
  const int m16 = lane & 15, quad = lane >> 4;

  // frag address (elems): Wf + nt*(16*512) + s*512
  const unsigned short* Wf = Wt1 + (size_t)((ge * 64 + jt * 8 + wave * 2) * 16) * 512 + lane * 8;
  float bv[2];
  #pragma unroll
  for (int nt = 0; nt < 2; nt++) bv[nt] = b1[ge * H_M + j0 + wave * 32 + nt * 16 + m16];

  for (int t0 = 0; t0 < n; t0 += 64) {
    __syncthreads();
    if (tid < 64) {
      int idx = t0 + tid;
      tokTS[tid] = list[ge * CAP + (idx < n ? idx : n - 1)];
    }
    __syncthreads();
    // stage x (fp32 -> bf16): thread covers token tid>>2, k-lane (tid&3)*4, 32 reps of 16 floats
    {
      const int trow = tid >> 2;
      const int kb = (tid & 3) * 4;
      const float* xr = x + (size_t)(tokTS[trow] >> 2) * D_M + kb;
      unsigned short* dst = &xl[trow * LDK + kb];
      #pragma unroll 8
      for (int rep = 0; rep < 32; rep++) {
        f32x4 v = *(const f32x4*)(xr + rep * 16);
        uint2 p = { pack2(v.x, v.y), pack2(v.z, v.w) };
        *(uint2*)(dst + rep * 16) = p;
      }
    }
    __syncthreads();

    f32x4 acc[4][2] = {};
    bf16x8 wA0, wA1, wB0, wB1;    // named regs: W frags for steps s (A) and s+1 (B)
    wA0 = *(const bf16x8*)(Wf);
    wA1 = *(const bf16x8*)(Wf + 16 * 512);
    wB0 = *(const bf16x8*)(Wf + 512);
    wB1 = *(const bf16x8*)(Wf + 16 * 512 + 512);

    for (int s2 = 0; s2 < 16; s2 += 2) {       // two K-steps per iter, 2-deep prefetch
      bf16x8 wN0, wN1, wM0, wM1;
      if (s2 + 2 < 16) {
        wN0 = *(const bf16x8*)(Wf + (s2 + 2) * 512);
        wN1 = *(const bf16x8*)(Wf + 16 * 512 + (s2 + 2) * 512);
      }
      #pragma unroll
      for (int mt = 0; mt < 4; mt++) {
        bf16x8 af = *(bf16x8*)&xl[(mt * 16 + m16) * LDK + s2 * 32 + quad * 8];
        acc[mt][0] = __builtin_amdgcn_mfma_f32_16x16x32_bf16(af, wA0, acc[mt][0], 0, 0, 0);
        acc[mt][1] = __builtin_amdgcn_mfma_f32_16x16x32_bf16(af, wA1, acc[mt][1], 0, 0, 0);
      }
      if (s2 + 3 < 16) {
        wM0 = *(const bf16x8*)(Wf + (s2 + 3) * 512);
        wM1 = *(const bf16x8*)(Wf + 16 * 512 + (s2 + 3) * 512);
      }
      #pragma unroll
      for (int mt = 0; mt < 4; mt++) {
        bf16x8 af = *(bf16x8*)&xl[(mt * 16 + m16) * LDK + (s2 + 1) * 32 + quad * 8];
        acc[mt][0] = __builtin_amdgcn_mfma_f32_16x16x32_bf16(af, wB0, acc[mt][0], 0, 0, 0);
        acc[mt][1] = __builtin_amdgcn_mfma_f32_16x16x32_bf16(af, wB1, acc[mt][1], 0, 0, 0);
      }
      wA0 = wN0; wA1 = wN1; wB0 = wM0; wB1 = wM1;
    }
    // epilogue: bias + relu -> bf16
    #pragma unroll
    for (int mt = 0; mt < 4; mt++)
      #pragma unroll
      for (int i = 0; i < 4; i++) {
        const int tr = mt * 16 + quad * 4 + i;
        if (t0 + tr < n) {
          const int ts = tokTS[tr];
          unsigned short* hp = h_ws + (size_t)ts * H_M + j0 + wave * 32 + m16;
          #pragma unroll
          for (int nt = 0; nt < 2; nt++) {
            float v = acc[mt][nt][i] + bv[nt];
            hp[nt * 16] = f2bf(v > 0.f ? v : 0.f);
          }
        }
      }
  }
}

// ---------------- GEMM2: y_part = h @ W2 (+b2 on ks=0) -> fp32, K-split 2, prepacked W ----------------
// grid: 64 ge x 4 j-tiles(128) x 2 ksplit.
__global__ __launch_bounds__(256, 2) void k_mlp2(
    const unsigned short* __restrict__ h_ws, const unsigned short* __restrict__ Wt2,
    const float* __restrict__ b2, const int* __restrict__ counts,
    const int* __restrict__ list, float* __restrict__ y0,
    float* __restrict__ y1) {
  const int ge = blockIdx.x >> 3;
  const int jtile = (blockIdx.x >> 1) & 3;
  const int j0 = jtile * 128;
  const int ks = blockIdx.x & 1;
  const int n = counts[ge];
  if (n == 0) return;
  __shared__ unsigned short xl[64 * LDK];   // [token][k-half], bf16
  __shared__ int tokTS[64];
  const int tid = threadIdx.x;
  const int lane = tid & 63, wave = tid >> 6;
  const int m16 = lane & 15, quad = lane >> 4;

  // frag address (elems): Wf + nt*(32*512) + s*512 ; s base = ks*16
  const unsigned short* Wf = Wt2 + (size_t)((ge * 32 + jtile * 8 + wave * 2) * 32 + ks * 16) * 512 + lane * 8;
  float bv[2];
  #pragma unroll
  for (int nt = 0; nt < 2; nt++)
    bv[nt] = ks == 0 ? b2[ge * D_M + j0 + wave * 32 + nt * 16 + m16] : 0.f;
  float* yk = ks == 0 ? y0 : y1;

  for (int t0 = 0; t0 < n; t0 += 64) {
    __syncthreads();
    if (tid < 64) {
      int idx = t0 + tid;
      tokTS[tid] = list[ge * CAP + (idx < n ? idx : n - 1)];
    }
    __syncthreads();
    // stage h-half (already bf16): thread covers token tid>>2, k-lane (tid&3)*8, 16 reps of 32 elems
    {
      const int trow = tid >> 2;
      const int kb = (tid & 3) * 8;
      const unsigned short* hr = h_ws + (size_t)tokTS[trow] * H_M + ks * 512 + kb;
      unsigned short* dst = &xl[trow * LDK + kb];
      #pragma unroll 8
      for (int rep = 0; rep < 16; rep++)
        *(u32x4*)(dst + rep * 32) = *(const u32x4*)(hr + rep * 32);
    }
    __syncthreads();

    f32x4 acc[4][2] = {};
    bf16x8 wA0, wA1, wB0, wB1;
    wA0 = *(const bf16x8*)(Wf);
    wA1 = *(const bf16x8*)(Wf + 32 * 512);
    wB0 = *(const bf16x8*)(Wf + 512);
    wB1 = *(const bf16x8*)(Wf + 32 * 512 + 512);

    for (int s2 = 0; s2 < 16; s2 += 2) {
      bf16x8 wN0, wN1, wM0, wM1;
      if (s2 + 2 < 16) {
        wN0 = *(const bf16x8*)(Wf + (s2 + 2) * 512);
        wN1 = *(const bf16x8*)(Wf + 32 * 512 + (s2 + 2) * 512);
      }
      #pragma unroll
      for (int mt = 0; mt < 4; mt++) {
        bf16x8 af = *(bf16x8*)&xl[(mt * 16 + m16) * LDK + s2 * 32 + quad * 8];
        acc[mt][0] = __builtin_amdgcn_mfma_f32_16x16x32_bf16(af, wA0, acc[mt][0], 0, 0, 0);
        acc[mt][1] = __builtin_amdgcn_mfma_f32_16x16x32_bf16(af, wA1, acc[mt][1], 0, 0, 0);
      }
      if (s2 + 3 < 16) {
        wM0 = *(const bf16x8*)(Wf + (s2 + 3) * 512);
        wM1 = *(const bf16x8*)(Wf + 32 * 512 + (s2 + 3) * 512);
      }
      #pragma unroll
      for (int mt = 0; mt < 4; mt++) {
        bf16x8 af = *(bf16x8*)&xl[(mt * 16 + m16) * LDK + (s2 + 1) * 32 + quad * 8];
        acc[mt][0] = __builtin_amdgcn_mfma_f32_16x16x32_bf16(af, wB0, acc[mt][0], 0, 0, 0);
        acc[mt][1] = __builtin_amdgcn_mfma_f32_16x16x32_bf16(af, wB1, acc[mt][1], 0, 0, 0);
      }
      wA0 = wN0; wA1 = wN1; wB0 = wM0; wB1 = wM1;
    }
    #pragma unroll
    for (int mt = 0; mt < 4; mt++)
      #pragma unroll
      for (int i = 0; i < 4; i++) {
        const int tr = mt * 16 + quad * 4 + i;
        if (t0 + tr < n) {
          const int ts = tokTS[tr];
          float* yp = yk + (size_t)ts * D_M + j0 + wave * 32 + m16;
          #pragma unroll
          for (int nt = 0; nt < 2; nt++)
            yp[nt * 16] = acc[mt][nt][i] + bv[nt];
        }
      }
  }
}

// ---------------- combine: out[t] = sum_s slotW[t,s] * (y0+y1)[t*4+s] ----------------
__global__ __launch_bounds__(256) void k_combine(
    const float* __restrict__ y0, const float* __restrict__ y1,
    const float* __restrict__ slotW, float* __restrict__ out) {
  const int idx = blockIdx.x * 256 + threadIdx.x;
  if (idx >= T_N * D_M / 4) return;
  const int t = idx >> 7;
  const int j = (idx & 127) * 4;
  float4 r = {0.f, 0.f, 0.f, 0.f};
  #pragma unroll
  for (int s = 0; s < 4; s++) {
    const float w = slotW[t * 4 + s];
    const size_t off = (size_t)(t * 4 + s) * D_M + j;
    const float4 a = *(const float4*)(y0 + off);
    const float4 b = *(const float4*)(y1 + off);
    r.x += w * (a.x + b.x);
    r.y += w * (a.y + b.y);
    r.z += w * (a.z + b.z);
    r.w += w * (a.w + b.w);
  }
  *(float4*)&out[(size_t)t * D_M + j] = r;
}

// ---------------- launch ----------------
extern "C" void kernel_launch(void* const* d_in, const int* in_sizes, int n_in,
                              void* d_out, int out_size, void* d_ws, size_t ws_size,
                              hipStream_t stream) {
  const float* x  = (const float*)d_in[0];
  const float* g1 = (const float*)d_in[1];
  const float* g2 = (const float*)d_in[2];
  const float* W1 = (const float*)d_in[3];
  const float* b1 = (const float*)d_in[4];
  const float* W2 = (const float*)d_in[5];
  const float* b2 = (const float*)d_in[6];
  float* out = (float*)d_out;

  char* ws = (char*)d_ws;
  float*          slotW  = (float*)(ws + 16384);               // 4096 floats
  int*            counts = (int*)(ws + 32768);                 // 64 ints
  int*            list   = (int*)(ws + 36864);                 // 64*1024 ints (256 KB)
  unsigned short* h_ws   = (unsigned short*)(ws + 524288);     // 4096*1024 bf16 (8 MB)
  float*          y0     = (float*)(ws + 524288 + 8388608);    // 4096*512 f32 (8 MB)
  float*          y1     = (float*)(ws + 524288 + 16777216);   // 4096*512 f32 (8 MB)
  unsigned short* Wt1    = (unsigned short*)(ws + 33554432);   // 64 MB bf16 fragment-packed
  unsigned short* Wt2    = (unsigned short*)(ws + 33554432 + 67108864); // 64 MB

  hipMemsetAsync(counts, 0, NEXP * sizeof(int), stream);
  k_route<<<T_N, 64, 0, stream>>>(x, g1, g2, slotW, counts, list);
  k_pack<<<1024, 256, 0, stream>>>(W1, W2, Wt1, Wt2);
  k_mlp1<<<NEXP * 8, 256, 0, stream>>>(x, Wt1, b1, counts, list, h_ws);
  k_mlp2<<<NEXP * 8, 256, 0, stream>>>(h_ws, Wt2, b2, counts, list, y0, y1);
  k_combine<<<(T_N * D_M / 4) / 256, 256, 0, stream>>>(y0, y1, slotW, out);
}

// Round 4
// 374.970 us; speedup vs baseline: 3.1196x; 1.1542x over previous
//
#include <hip/hip_runtime.h>
#include <hip/hip_bf16.h>

// Problem constants
#define D_M   512
#define H_M   1024
#define G_N   8
#define E_N   8
#define T_N   1024
#define NEXP  64
#define CAP   1024

#define LDK   520          // padded K row stride for xl (bf16 elems): 520*2=1040 B, 16B-aligned

typedef __attribute__((ext_vector_type(8))) short bf16x8;
typedef __attribute__((ext_vector_type(4))) float f32x4;
typedef __attribute__((ext_vector_type(4))) unsigned int u32x4;

// single-instruction packed f32->bf16 (RNE)
__device__ __forceinline__ unsigned pack2(float a, float b) {
  unsigned r;
  asm("v_cvt_pk_bf16_f32 %0, %1, %2" : "=v"(r) : "v"(a), "v"(b));
  return r;
}
__device__ __forceinline__ unsigned short f2bf(float f) {
  unsigned u = __builtin_bit_cast(unsigned, f);
  u = (u + 0x7fffu + ((u >> 16) & 1u)) >> 16;   // RTN-even
  return (unsigned short)u;
}

// ---------------- routing (fp32, exact) + expert-list build (merged) ----------------
__global__ __launch_bounds__(64) void k_route(
    const float* __restrict__ x, const float* __restrict__ g1,
    const float* __restrict__ g2, float* __restrict__ slotW,
    int* __restrict__ counts, int* __restrict__ list) {
  __shared__ float xs[D_M];
  __shared__ float l2s[G_N][E_N];
  __shared__ float l1s[G_N];
  __shared__ float l1part[G_N][8];
  const int t = blockIdx.x;
  const int lane = threadIdx.x;
  const float* xr = x + (size_t)t * D_M;
  for (int i = lane; i < D_M; i += 64) xs[i] = xr[i];
  __syncthreads();
  {
    const int g = lane >> 3, e = lane & 7;
    const float* gp = g2 + (size_t)g * D_M * E_N + e;
    float acc = 0.f;
    #pragma unroll 8
    for (int i = 0; i < D_M; i++) acc += xs[i] * gp[(size_t)i * E_N];
    l2s[g][e] = acc;
  }
  {
    const int g = lane >> 3, c = lane & 7;
    float acc = 0.f;
    #pragma unroll 8
    for (int i = c * 64; i < c * 64 + 64; i++) acc += xs[i] * g1[(size_t)i * G_N + g];
    l1part[g][c] = acc;
  }
  __syncthreads();
  if (lane < G_N) {
    float s = 0.f;
    #pragma unroll
    for (int c = 0; c < 8; c++) s += l1part[lane][c];
    l1s[lane] = s;
  }
  __syncthreads();
  if (lane == 0) {
    int a1 = 0;
    for (int g = 1; g < G_N; g++) if (l1s[g] > l1s[a1]) a1 = g;
    int a2 = (a1 == 0) ? 1 : 0;
    for (int g = 0; g < G_N; g++) if (g != a1 && l1s[g] > l1s[a2]) a2 = g;
    const float m = l1s[a1];
    float w1a = __expf(l1s[a1] - m), w1b = __expf(l1s[a2] - m);
    const float inv = 1.f / (w1a + w1b);
    w1a *= inv; w1b *= inv;
    const int gsel[2] = {a1, a2};
    const float wsel[2] = {w1a, w1b};
    for (int a = 0; a < 2; a++) {
      const int g = gsel[a];
      int e1 = 0;
      for (int e = 1; e < E_N; e++) if (l2s[g][e] > l2s[g][e1]) e1 = e;
      int e2 = (e1 == 0) ? 1 : 0;
      for (int e = 0; e < E_N; e++) if (e != e1 && l2s[g][e] > l2s[g][e2]) e2 = e;
      const float mm = l2s[g][e1];
      float ua = __expf(l2s[g][e1] - mm), ub = __expf(l2s[g][e2] - mm);
      const float uin = 1.f / (ua + ub);
      ua *= uin; ub *= uin;
      const int ge0 = g * E_N + e1;
      const int ge1 = g * E_N + e2;
      slotW[t * 4 + a * 2 + 0] = wsel[a] * ua;
      slotW[t * 4 + a * 2 + 1] = wsel[a] * ub;
      int p0 = atomicAdd(&counts[ge0], 1);
      list[ge0 * CAP + p0] = t * 4 + a * 2 + 0;
      int p1 = atomicAdd(&counts[ge1], 1);
      list[ge1 * CAP + p1] = t * 4 + a * 2 + 1;
    }
  }
}

// ---------------- GEMM1: h = relu(x @ W1 + b1) -> bf16. W fp32 -> bf16 frags in REGISTERS ----------------
// grid: 64 ge x 8 j-tiles(128). block 256 = 4 waves; wave owns 32 j (nt=2), all 64 tokens (mt=4).
// Each wave loads its 32 W-frags (2 nt x 16 s) once into VGPRs (256 independent scalar loads,
// each wave-instr = 4 fully-used 64B segments), packs via v_cvt_pk_bf16_f32, reuses across t-loop.
__global__ __launch_bounds__(256, 1) void k_mlp1(
    const float* __restrict__ x, const float* __restrict__ W1,
    const float* __restrict__ b1, const int* __restrict__ counts,
    const int* __restrict__ list, unsigned short* __restrict__ h_ws) {
  const int ge = blockIdx.x >> 3;
  const int jt = blockIdx.x & 7;
  const int j0 = jt * 128;
  const int n = counts[ge];
  if (n == 0) return;
  __shared__ unsigned short xl[64 * LDK];   // [token][k] full-K, bf16
  __shared__ int tokTS[64];
  const int tid = threadIdx.x;
  const int lane = tid & 63, wave = tid >> 6;
  const int m16 = lane & 15, quad = lane >> 4;

  const float* Wcol = W1 + (size_t)ge * (D_M * H_M) + j0 + wave * 32 + m16;
  float bv[2];
  #pragma unroll
  for (int nt = 0; nt < 2; nt++) bv[nt] = b1[ge * H_M + j0 + wave * 32 + nt * 16 + m16];

  // ---- W prologue: 32 frags resident in registers ----
  bf16x8 wf0[16], wf1[16];
  #pragma unroll
  for (int s = 0; s < 16; s++) {
    float v[8], w[8];
    #pragma unroll
    for (int i = 0; i < 8; i++) v[i] = Wcol[(size_t)(s * 32 + quad * 8 + i) * H_M];
    #pragma unroll
    for (int i = 0; i < 8; i++) w[i] = Wcol[(size_t)(s * 32 + quad * 8 + i) * H_M + 16];
    u32x4 pa = { pack2(v[0], v[1]), pack2(v[2], v[3]), pack2(v[4], v[5]), pack2(v[6], v[7]) };
    u32x4 pb = { pack2(w[0], w[1]), pack2(w[2], w[3]), pack2(w[4], w[5]), pack2(w[6], w[7]) };
    wf0[s] = __builtin_bit_cast(bf16x8, pa);
    wf1[s] = __builtin_bit_cast(bf16x8, pb);
  }

  for (int t0 = 0; t0 < n; t0 += 64) {
    __syncthreads();
    if (tid < 64) {
      int idx = t0 + tid;
      tokTS[tid] = list[ge * CAP + (idx < n ? idx : n - 1)];
    }
    __syncthreads();
    // stage x (fp32 -> bf16): thread covers token tid>>2, k-lane (tid&3)*4, 32 reps of 16 floats
    {
      const int trow = tid >> 2;
      const int kb = (tid & 3) * 4;
      const float* xr = x + (size_t)(tokTS[trow] >> 2) * D_M + kb;
      unsigned short* dst = &xl[trow * LDK + kb];
      #pragma unroll 8
      for (int rep = 0; rep < 32; rep++) {
        f32x4 v = *(const f32x4*)(xr + rep * 16);
        uint2 p = { pack2(v.x, v.y), pack2(v.z, v.w) };
        *(uint2*)(dst + rep * 16) = p;
      }
    }
    __syncthreads();

    f32x4 acc[4][2] = {};
    #pragma unroll
    for (int s = 0; s < 16; s++) {
      #pragma unroll
      for (int mt = 0; mt < 4; mt++) {
        bf16x8 af = *(bf16x8*)&xl[(mt * 16 + m16) * LDK + s * 32 + quad * 8];
        acc[mt][0] = __builtin_amdgcn_mfma_f32_16x16x32_bf16(af, wf0[s], acc[mt][0], 0, 0, 0);
        acc[mt][1] = __builtin_amdgcn_mfma_f32_16x16x32_bf16(af, wf1[s], acc[mt][1], 0, 0, 0);
      }
    }
    // epilogue: bias + relu -> bf16
    #pragma unroll
    for (int mt = 0; mt < 4; mt++)
      #pragma unroll
      for (int i = 0; i < 4; i++) {
        const int tr = mt * 16 + quad * 4 + i;
        if (t0 + tr < n) {
          const int ts = tokTS[tr];
          unsigned short* hp = h_ws + (size_t)ts * H_M + j0 + wave * 32 + m16;
          #pragma unroll
          for (int nt = 0; nt < 2; nt++) {
            float v = acc[mt][nt][i] + bv[nt];
            hp[nt * 16] = f2bf(v > 0.f ? v : 0.f);
          }
        }
      }
  }
}

// ---------------- GEMM2: y_part = h @ W2 (+b2 on ks=0) -> fp32, K-split 2, W frags in registers ----------------
// grid: 64 ge x 4 j-tiles(128) x 2 ksplit.
__global__ __launch_bounds__(256, 1) void k_mlp2(
    const unsigned short* __restrict__ h_ws, const float* __restrict__ W2,
    const float* __restrict__ b2, const int* __restrict__ counts,
    const int* __restrict__ list, float* __restrict__ y0,
    float* __restrict__ y1) {
  const int ge = blockIdx.x >> 3;
  const int jtile = (blockIdx.x >> 1) & 3;
  const int j0 = jtile * 128;
  const int ks = blockIdx.x & 1;
  const int n = counts[ge];
  if (n == 0) return;
  __shared__ unsigned short xl[64 * LDK];   // [token][k-half], bf16
  __shared__ int tokTS[64];
  const int tid = threadIdx.x;
  const int lane = tid & 63, wave = tid >> 6;
  const int m16 = lane & 15, quad = lane >> 4;

  const float* Wcol = W2 + (size_t)ge * (H_M * D_M) + (size_t)(ks * 512) * D_M + j0 + wave * 32 + m16;
  float bv[2];
  #pragma unroll
  for (int nt = 0; nt < 2; nt++)
    bv[nt] = ks == 0 ? b2[ge * D_M + j0 + wave * 32 + nt * 16 + m16] : 0.f;
  float* yk = ks == 0 ? y0 : y1;

  // ---- W prologue: 32 frags resident in registers ----
  bf16x8 wf0[16], wf1[16];
  #pragma unroll
  for (int s = 0; s < 16; s++) {
    float v[8], w[8];
    #pragma unroll
    for (int i = 0; i < 8; i++) v[i] = Wcol[(size_t)(s * 32 + quad * 8 + i) * D_M];
    #pragma unroll
    for (int i = 0; i < 8; i++) w[i] = Wcol[(size_t)(s * 32 + quad * 8 + i) * D_M + 16];
    u32x4 pa = { pack2(v[0], v[1]), pack2(v[2], v[3]), pack2(v[4], v[5]), pack2(v[6], v[7]) };
    u32x4 pb = { pack2(w[0], w[1]), pack2(w[2], w[3]), pack2(w[4], w[5]), pack2(w[6], w[7]) };
    wf0[s] = __builtin_bit_cast(bf16x8, pa);
    wf1[s] = __builtin_bit_cast(bf16x8, pb);
  }

  for (int t0 = 0; t0 < n; t0 += 64) {
    __syncthreads();
    if (tid < 64) {
      int idx = t0 + tid;
      tokTS[tid] = list[ge * CAP + (idx < n ? idx : n - 1)];
    }
    __syncthreads();
    // stage h-half (already bf16): thread covers token tid>>2, k-lane (tid&3)*8, 16 reps of 32 elems
    {
      const int trow = tid >> 2;
      const int kb = (tid & 3) * 8;
      const unsigned short* hr = h_ws + (size_t)tokTS[trow] * H_M + ks * 512 + kb;
      unsigned short* dst = &xl[trow * LDK + kb];
      #pragma unroll 8
      for (int rep = 0; rep < 16; rep++)
        *(u32x4*)(dst + rep * 32) = *(const u32x4*)(hr + rep * 32);
    }
    __syncthreads();

    f32x4 acc[4][2] = {};
    #pragma unroll
    for (int s = 0; s < 16; s++) {
      #pragma unroll
      for (int mt = 0; mt < 4; mt++) {
        bf16x8 af = *(bf16x8*)&xl[(mt * 16 + m16) * LDK + s * 32 + quad * 8];
        acc[mt][0] = __builtin_amdgcn_mfma_f32_16x16x32_bf16(af, wf0[s], acc[mt][0], 0, 0, 0);
        acc[mt][1] = __builtin_amdgcn_mfma_f32_16x16x32_bf16(af, wf1[s], acc[mt][1], 0, 0, 0);
      }
    }
    #pragma unroll
    for (int mt = 0; mt < 4; mt++)
      #pragma unroll
      for (int i = 0; i < 4; i++) {
        const int tr = mt * 16 + quad * 4 + i;
        if (t0 + tr < n) {
          const int ts = tokTS[tr];
          float* yp = yk + (size_t)ts * D_M + j0 + wave * 32 + m16;
          #pragma unroll
          for (int nt = 0; nt < 2; nt++)
            yp[nt * 16] = acc[mt][nt][i] + bv[nt];
        }
      }
  }
}

// ---------------- combine: out[t] = sum_s slotW[t,s] * (y0+y1)[t*4+s] ----------------
__global__ __launch_bounds__(256) void k_combine(
    const float* __restrict__ y0, const float* __restrict__ y1,
    const float* __restrict__ slotW, float* __restrict__ out) {
  const int idx = blockIdx.x * 256 + threadIdx.x;
  if (idx >= T_N * D_M / 4) return;
  const int t = idx >> 7;
  const int j = (idx & 127) * 4;
  float4 r = {0.f, 0.f, 0.f, 0.f};
  #pragma unroll
  for (int s = 0; s < 4; s++) {
    const float w = slotW[t * 4 + s];
    const size_t off = (size_t)(t * 4 + s) * D_M + j;
    const float4 a = *(const float4*)(y0 + off);
    const float4 b = *(const float4*)(y1 + off);
    r.x += w * (a.x + b.x);
    r.y += w * (a.y + b.y);
    r.z += w * (a.z + b.z);
    r.w += w * (a.w + b.w);
  }
  *(float4*)&out[(size_t)t * D_M + j] = r;
}

// ---------------- launch ----------------
extern "C" void kernel_launch(void* const* d_in, const int* in_sizes, int n_in,
                              void* d_out, int out_size, void* d_ws, size_t ws_size,
                              hipStream_t stream) {
  const float* x  = (const float*)d_in[0];
  const float* g1 = (const float*)d_in[1];
  const float* g2 = (const float*)d_in[2];
  const float* W1 = (const float*)d_in[3];
  const float* b1 = (const float*)d_in[4];
  const float* W2 = (const float*)d_in[5];
  const float* b2 = (const float*)d_in[6];
  float* out = (float*)d_out;

  char* ws = (char*)d_ws;
  float*          slotW  = (float*)(ws + 16384);               // 4096 floats
  int*            counts = (int*)(ws + 32768);                 // 64 ints
  int*            list   = (int*)(ws + 36864);                 // 64*1024 ints (256 KB)
  unsigned short* h_ws   = (unsigned short*)(ws + 524288);     // 4096*1024 bf16 (8 MB)
  float*          y0     = (float*)(ws + 524288 + 8388608);    // 4096*512 f32 (8 MB)
  float*          y1     = (float*)(ws + 524288 + 16777216);   // 4096*512 f32 (8 MB)

  hipMemsetAsync(counts, 0, NEXP * sizeof(int), stream);
  k_route<<<T_N, 64, 0, stream>>>(x, g1, g2, slotW, counts, list);
  k_mlp1<<<NEXP * 8, 256, 0, stream>>>(x, W1, b1, counts, list, h_ws);
  k_mlp2<<<NEXP * 8, 256, 0, stream>>>(h_ws, W2, b2, counts, list, y0, y1);
  k_combine<<<(T_N * D_M / 4) / 256, 256, 0, stream>>>(y0, y1, slotW, out);
}